// Round 6
// baseline (9140.105 us; speedup 1.0000x reference)
//
#include <hip/hip_runtime.h>
#include <hip/hip_bf16.h>

// Problem dims
#define BB 256
#define KK 512
#define UU 16
#define PP 64
#define HH 256
#define LL 64
#define THD 128   // 2*P
#define G3 768    // 3*H
#define NT 1024   // threads per block (16 waves, 4 waves/EU, VGPR budget 128)
#define WIH_P 66  // W_ih row pitch in halfs (33 dwords)

typedef _Float16 half_t;
typedef _Float16 v2h __attribute__((ext_vector_type(2)));
typedef _Float16 v8h __attribute__((ext_vector_type(8)));

#define P2H(v, i) __builtin_shufflevector((v), (v), 2 * (i), 2 * (i) + 1)

#define REP4(M)  M(0) M(1) M(2) M(3)
#define REP8(M)  REP4(M) M(4) M(5) M(6) M(7)
#define REP16(M) REP8(M) M(8) M(9) M(10) M(11) M(12) M(13) M(14) M(15)

// packed f16 dot2 with fp32 accumulate
__device__ __forceinline__ float fdot2(v2h a, v2h b, float c) {
#if __has_builtin(__builtin_amdgcn_fdot2)
  return __builtin_amdgcn_fdot2(a, b, c, false);
#else
  return fmaf((float)a.x, (float)b.x, fmaf((float)a.y, (float)b.y, c));
#endif
}

__device__ __forceinline__ float sigm(float x) { return 1.f / (1.f + __expf(-x)); }

// load float2 from global, convert to packed f16 pair
__device__ __forceinline__ v2h ld2(const float2* p) {
  float2 f = *p;
  v2h v; v.x = (half_t)f.x; v.y = (half_t)f.y;
  return v;
}

struct SM {
  alignas(16) half_t wih[G3 * WIH_P];  // W_ih rows, pitch 66 halfs
  alignas(16) float  wlt[80 * 65];     // W_lift transposed [f][j], pitch 65
  alignas(16) float  jmp[UU * PP];     // jump [u][p]
  float b_ih[G3];
  float b_hh[G3];
  float b_lift[LL];
  float b_head[THD];
  float gi[G3];
  float gh[G3];
  alignas(16) float  h[HH];
  alignas(16) half_t h16[HH];
  alignas(16) half_t x16[LL];
  float theta[THD];
  float y[PP];
  float ypre[PP];
  float us[2][UU];
  float dts[2];
};

__global__
__attribute__((amdgpu_flat_work_group_size(NT, NT)))
void odernn_kernel(
    const float* __restrict__ y0, const float* __restrict__ u_seq,
    const float* __restrict__ dt_seq, const float* __restrict__ W_lift,
    const float* __restrict__ b_lift, const float* __restrict__ W_ih,
    const float* __restrict__ b_ih, const float* __restrict__ W_hh,
    const float* __restrict__ b_hh, const float* __restrict__ W_head,
    const float* __restrict__ b_head, const float* __restrict__ jump,
    float* __restrict__ out_y, float* __restrict__ out_th) {
  __shared__ SM sm;
  const int b = blockIdx.x;
  const int t = threadIdx.x;

  // P2 mapping: group g = t>>2 (4 threads) owns gate rows {3g, 3g+1, 3g+2}.
  // Thread l = t&3 holds: FULL half-row (row 3g+(l>>1), K-half l&1, 64 v2h)
  //                     + QUARTER l of row 3g+2 (32 v2h).
  const int g = t >> 2, l = t & 3;
  const int r0 = 3 * g, r1 = 3 * g + 1, r2 = 3 * g + 2;
  const int rf = 3 * g + (l >> 1);   // full half-row's row
  const int hf = l & 1;              // which K-half of that row
  // P4 mapping: 8 threads per W_head row.
  const int hr = t >> 3, hl = t & 7;

  // ---- register-resident weights: 112 NAMED v2h values ----
  const float2* w2 = (const float2*)W_hh;
  const float2* wh = (const float2*)W_head;
  const int fb = rf * 128 + hf * 64;  // float2 base of full half-row
  const int qb = r2 * 128 + l * 32;   // quarter of row r2
  const int db = hr * 128 + hl * 16;  // eighth of W_head row hr

#define DECL_WF(q) v2h wfa##q = ld2(w2 + fb + 4 * q),     \
                       wfb##q = ld2(w2 + fb + 4 * q + 1), \
                       wfc##q = ld2(w2 + fb + 4 * q + 2), \
                       wfd##q = ld2(w2 + fb + 4 * q + 3);
  REP16(DECL_WF)   // 64 v2h
#define DECL_WQ(q) v2h wqa##q = ld2(w2 + qb + 4 * q),     \
                       wqb##q = ld2(w2 + qb + 4 * q + 1), \
                       wqc##q = ld2(w2 + qb + 4 * q + 2), \
                       wqd##q = ld2(w2 + qb + 4 * q + 3);
  REP8(DECL_WQ)    // 32 v2h
#define DECL_WD(q) v2h wda##q = ld2(wh + db + 4 * q),     \
                       wdb##q = ld2(wh + db + 4 * q + 1), \
                       wdc##q = ld2(wh + db + 4 * q + 2), \
                       wdd##q = ld2(wh + db + 4 * q + 3);
  REP4(DECL_WD)    // 16 v2h

  // ---- LDS init ----
  for (int i = t; i < G3 * 64; i += NT) {
    int r = i >> 6, c = i & 63;
    sm.wih[r * WIH_P + c] = (half_t)W_ih[i];
  }
  for (int i = t; i < 64 * 80; i += NT) {
    int j = i / 80, f = i - j * 80;
    sm.wlt[f * 65 + j] = W_lift[i];
  }
  for (int i = t; i < UU * PP; i += NT) sm.jmp[i] = jump[i];
  if (t < G3) { sm.b_ih[t] = b_ih[t]; sm.b_hh[t] = b_hh[t]; }
  if (t < LL) sm.b_lift[t] = b_lift[t];
  if (t < THD) sm.b_head[t] = b_head[t];
  if (t < HH) { sm.h[t] = 0.f; sm.h16[t] = (half_t)0.f; }
  if (t < PP) sm.y[t] = y0[b * PP + t];
  if (t < UU) sm.us[0][t] = u_seq[(size_t)b * KK * UU + t];
  if (t == UU) sm.dts[0] = dt_seq[(size_t)b * KK];
  __syncthreads();

#pragma unroll 1
  for (int k = 0; k < KK; ++k) {
    const int cb = k & 1;

    // ---- P1: lift (512 threads, 8 per output) + jump-pre (64 threads) ----
    if (t < 512) {
      const int j = t >> 3, part = t & 7;
      const int f0 = part * 10;
      float acc = 0.f;
#pragma unroll
      for (int c = 0; c < 10; ++c) {
        int f = f0 + c;
        float fv = (f < UU) ? sm.us[cb][f] : sm.y[f - UU];
        acc = fmaf(fv, sm.wlt[f * 65 + j], acc);
      }
      acc += __shfl_xor(acc, 1);
      acc += __shfl_xor(acc, 2);
      acc += __shfl_xor(acc, 4);
      if (part == 0) {
        float v = acc + sm.b_lift[j];
        sm.x16[j] = (half_t)(v * sigm(v));   // silu
      }
    } else if (t < 576) {
      const int i = t - 512;
      float acc = sm.y[i];
#pragma unroll
      for (int u = 0; u < UU; ++u) acc = fmaf(sm.us[cb][u], sm.jmp[u * PP + i], acc);
      sm.ypre[i] = acc;                       // y_prev + u_k @ jump
    }
    __syncthreads();

    // ---- P2: gh = W_hh@h + b_hh ; gi = W_ih@x + b_ih ----
    {
      const v8h* hp8 = (const v8h*)sm.h16;   // 32 b128 units
      // FULL half-row: 64 dots, 2 chains
      const v8h* hf8 = hp8 + hf * 16;
      float a0 = 0.f, a1 = 0.f;
#define DOT_WF(q) { v8h hv = hf8[q];                  \
      a0 = fdot2(wfa##q, P2H(hv, 0), a0);             \
      a1 = fdot2(wfb##q, P2H(hv, 1), a1);             \
      a0 = fdot2(wfc##q, P2H(hv, 2), a0);             \
      a1 = fdot2(wfd##q, P2H(hv, 3), a1); }
      REP16(DOT_WF)
      float af = a0 + a1;
      // QUARTER of row r2: 32 dots
      const v8h* hq8 = hp8 + l * 8;
      float q0 = 0.f, q1 = 0.f;
#define DOT_WQ(q) { v8h hv = hq8[q];                  \
      q0 = fdot2(wqa##q, P2H(hv, 0), q0);             \
      q1 = fdot2(wqb##q, P2H(hv, 1), q1);             \
      q0 = fdot2(wqc##q, P2H(hv, 2), q0);             \
      q1 = fdot2(wqd##q, P2H(hv, 3), q1); }
      REP8(DOT_WQ)
      float aq = q0 + q1;
      // W_ih from LDS: quarter l of rows r0,r1,r2 (8 v2h each)
      const v2h* xq  = (const v2h*)sm.x16 + l * 8;
      const v2h* wi0 = (const v2h*)sm.wih + r0 * 33 + l * 8;
      const v2h* wi1 = (const v2h*)sm.wih + r1 * 33 + l * 8;
      const v2h* wi2 = (const v2h*)sm.wih + r2 * 33 + l * 8;
      float ai0 = 0.f, ai1 = 0.f, ai2 = 0.f;
#pragma unroll
      for (int w = 0; w < 8; ++w) {
        v2h xv = xq[w];
        ai0 = fdot2(wi0[w], xv, ai0);
        ai1 = fdot2(wi1[w], xv, ai1);
        ai2 = fdot2(wi2[w], xv, ai2);
      }
      // reductions
      af += __shfl_xor(af, 1);               // (l0,l1)->row r0 ; (l2,l3)->row r1
      aq += __shfl_xor(aq, 1);
      aq += __shfl_xor(aq, 2);               // all 4 -> row r2
      ai0 += __shfl_xor(ai0, 1); ai0 += __shfl_xor(ai0, 2);
      ai1 += __shfl_xor(ai1, 1); ai1 += __shfl_xor(ai1, 2);
      ai2 += __shfl_xor(ai2, 1); ai2 += __shfl_xor(ai2, 2);
      if (l == 0) { sm.gh[r0] = af + sm.b_hh[r0]; sm.gi[r0] = ai0 + sm.b_ih[r0]; }
      if (l == 2) { sm.gh[r1] = af + sm.b_hh[r1]; sm.gi[r1] = ai1 + sm.b_ih[r1]; }
      if (l == 1) { sm.gh[r2] = aq + sm.b_hh[r2]; sm.gi[r2] = ai2 + sm.b_ih[r2]; }
    }
    __syncthreads();

    // ---- P3: GRU gates (256 threads) + prefetch next u/dt ----
    if (t < 256) {
      float r = sigm(sm.gi[t] + sm.gh[t]);
      float z = sigm(sm.gi[256 + t] + sm.gh[256 + t]);
      float pre = sm.gi[512 + t] + r * sm.gh[512 + t];
      float n = 2.f * sigm(2.f * pre) - 1.f;  // tanh
      float hn = (1.f - z) * n + z * sm.h[t];
      sm.h[t] = hn;
      sm.h16[t] = (half_t)hn;
    } else if (k + 1 < KK && t >= 256 && t < 256 + UU) {
      sm.us[cb ^ 1][t - 256] =
          u_seq[(size_t)b * KK * UU + (size_t)(k + 1) * UU + (t - 256)];
    } else if (k + 1 < KK && t == 256 + UU) {
      sm.dts[cb ^ 1] = dt_seq[(size_t)b * KK + (k + 1)];
    }
    __syncthreads();

    // ---- P4: head -> theta (8 threads per output) ----
    {
      const v8h* hd8 = (const v8h*)sm.h16 + hl * 4;
      float c0 = 0.f, c1 = 0.f;
#define DOT_WD(q) { v8h hv = hd8[q];                  \
      c0 = fdot2(wda##q, P2H(hv, 0), c0);             \
      c1 = fdot2(wdb##q, P2H(hv, 1), c1);             \
      c0 = fdot2(wdc##q, P2H(hv, 2), c0);             \
      c1 = fdot2(wdd##q, P2H(hv, 3), c1); }
      REP4(DOT_WD)
      float acc = c0 + c1;
      acc += __shfl_xor(acc, 1);
      acc += __shfl_xor(acc, 2);
      acc += __shfl_xor(acc, 4);
      if (hl == 0) {
        float raw = acc + sm.b_head[hr];
        sm.theta[hr] = 0.001f + 1.999f * sigm(raw);
      }
    }
    __syncthreads();

    // ---- P5: RK4 + clamp + global stores (f32 outputs) ----
    if (t < PP) {
      float a = sm.theta[t], dr = sm.theta[PP + t];
      float yv = sm.ypre[t];
      float hdt = sm.dts[cb];
      float k1 = dr - a * yv;
      float k2 = dr - a * fmaf(0.5f * hdt, k1, yv);
      float k3 = dr - a * fmaf(0.5f * hdt, k2, yv);
      float k4 = dr - a * fmaf(hdt, k3, yv);
      yv = yv + (hdt * (1.f / 6.f)) * (k1 + 2.f * k2 + 2.f * k3 + k4);
      yv = fmaxf(yv, 0.f);
      sm.y[t] = yv;
      out_y[(size_t)b * KK * PP + (size_t)k * PP + t] = yv;
    } else if (t < 64 + THD) {
      int j = t - 64;
      out_th[(size_t)b * KK * THD + (size_t)k * THD + j] = sm.theta[j];
    }
    __syncthreads();
  }
}

extern "C" void kernel_launch(void* const* d_in, const int* in_sizes, int n_in,
                              void* d_out, int out_size, void* d_ws, size_t ws_size,
                              hipStream_t stream) {
  (void)in_sizes; (void)n_in; (void)d_ws; (void)ws_size; (void)out_size;
  const float* y0     = (const float*)d_in[0];
  const float* u_seq  = (const float*)d_in[1];
  const float* dt_seq = (const float*)d_in[2];
  const float* W_lift = (const float*)d_in[3];
  const float* b_lift = (const float*)d_in[4];
  const float* W_ih   = (const float*)d_in[5];
  const float* b_ih   = (const float*)d_in[6];
  const float* W_hh   = (const float*)d_in[7];
  const float* b_hh   = (const float*)d_in[8];
  const float* W_head = (const float*)d_in[9];
  const float* b_head = (const float*)d_in[10];
  const float* jump   = (const float*)d_in[11];
  float* out  = (float*)d_out;
  float* outy = out;
  float* outt = out + (size_t)BB * KK * PP;
  odernn_kernel<<<dim3(BB), dim3(NT), 0, stream>>>(
      y0, u_seq, dt_seq, W_lift, b_lift, W_ih, b_ih, W_hh, b_hh,
      W_head, b_head, jump, outy, outt);
}

// Round 8
// 5168.798 us; speedup vs baseline: 1.7683x; 1.7683x over previous
//
#include <hip/hip_runtime.h>
#include <hip/hip_bf16.h>

// Problem dims
#define BB 256
#define KK 512
#define UU 16
#define PP 64
#define HH 256
#define LL 64
#define THD 128   // 2*P
#define G3 768    // 3*H
#define MB 16     // batch rows per block
#define NG (BB/MB)  // 16 blocks
#define NT 512

// LDS row pitches (elements). All give 16B-aligned rows + benign bank spread.
#define HP 264    // h_M pitch (f16)
#define XP 72     // x_M pitch (f16)
#define FP 104    // feat pitch (f16)
#define TP 132    // theta pitch (f32)
#define YP 68     // y pitch (f32)

typedef _Float16 f16;
typedef _Float16 f16x8 __attribute__((ext_vector_type(8)));
typedef float f32x4 __attribute__((ext_vector_type(4)));

// fragment regions in d_ws (1KB per fragment = 64 lanes x 16B)
#define FR_WHH 0       // 48 nt * 8 kk = 384 frags
#define FR_WIH 384     // 48 nt * 2 kk = 96
#define FR_WHEAD 480   // 8 nt * 8 kk = 64
#define FR_WLIFT 544   // 4 nt * 3 kk = 12
#define FR_TOTAL 556
#define WS_REQ (FR_TOTAL * 1024)

__device__ __forceinline__ float sigm(float x) { return 1.f / (1.f + __expf(-x)); }

__device__ __forceinline__ f32x4 MFMA(f16x8 a, f16x8 b, f32x4 c) {
  return __builtin_amdgcn_mfma_f32_16x16x32_f16(a, b, c, 0, 0, 0);
}

// -------- pack kernel: all weights -> f16 MFMA-B fragments in d_ws --------
// Frag f, lane l, slot j at ws[f*512 + l*8 + j].
// B[k][n] = W[n][k]: n = nt*16 + (l&15), k = kk*32 + (l>>4)*8 + j.
__global__ void pack_kernel(const float* __restrict__ W_lift,
                            const float* __restrict__ W_ih,
                            const float* __restrict__ W_hh,
                            const float* __restrict__ W_head,
                            f16* __restrict__ ws) {
  int tid = blockIdx.x * 256 + threadIdx.x;
  if (tid >= FR_TOTAL * 512) return;
  int f = tid >> 9, l = (tid >> 3) & 63, j = tid & 7;
  int lm = l & 15, c8 = ((l >> 4) << 3) + j;
  float v;
  if (f < FR_WIH) { int nt = f >> 3, kk = f & 7; v = W_hh[(nt * 16 + lm) * 256 + kk * 32 + c8]; }
  else if (f < FR_WHEAD) { int f2 = f - FR_WIH; int nt = f2 >> 1, kk = f2 & 1;
    v = W_ih[(nt * 16 + lm) * 64 + kk * 32 + c8]; }
  else if (f < FR_WLIFT) { int f3 = f - FR_WHEAD; int nt = f3 >> 3, kk = f3 & 7;
    v = W_head[(nt * 16 + lm) * 256 + kk * 32 + c8]; }
  else { int f4 = f - FR_WLIFT; int nt = f4 / 3, kk = f4 % 3; int c = kk * 32 + c8;
    v = (c < UU + PP) ? W_lift[(nt * 16 + lm) * 80 + c] : 0.f; }
  ws[tid] = (f16)v;
}

// fallback b-frag from f32 weights (only when ws too small)
__device__ __forceinline__ f16x8 bfrag_f32(const float* W, int ldw, int n, int c) {
  const float* p = W + n * ldw + c;
  f16x8 r;
#pragma unroll
  for (int j = 0; j < 8; ++j) r[j] = (f16)p[j];
  return r;
}

struct SM {
  alignas(16) f16 h_M[MB * HP];      // row-major [m][c]
  alignas(16) f16 x_M[MB * XP];
  alignas(16) f16 f_M[MB * FP];      // feat = [u(16)|y(64)|pad]
  alignas(16) float theta[MB * TP];
  alignas(16) float y[MB * YP];
  alignas(16) float u[2][MB][UU];
  alignas(16) float jmp[UU * PP];
  float dt[2][MB];
  float bih[G3], bhh[G3], bhead[THD], blift[LL];
};

template<bool PACKED>
__global__ __launch_bounds__(NT) void odernn_mfma(
    const float* __restrict__ y0, const float* __restrict__ u_seq,
    const float* __restrict__ dt_seq, const float* __restrict__ W_lift,
    const float* __restrict__ b_lift, const float* __restrict__ W_ih,
    const float* __restrict__ b_ih, const float* __restrict__ W_hh,
    const float* __restrict__ b_hh, const float* __restrict__ W_head,
    const float* __restrict__ b_head, const float* __restrict__ jump,
    const f16* __restrict__ ws16,
    float* __restrict__ out_y, float* __restrict__ out_th) {
  __shared__ SM sm;
  const int t = threadIdx.x;
  const int lane = t & 63, wv = t >> 6;
  const int lm = lane & 15, lg = lane >> 4;
  const int g16 = blockIdx.x * MB;
  const f16x8* wsf = (const f16x8*)ws16;

#define BF(bb, FID) do { \
    if constexpr (PACKED) { bb = wsf[(FID) * 64 + lane]; } \
    else { int fid_ = (FID); int c8_ = lg << 3; \
      if (fid_ < FR_WIH) { int nt_ = fid_ >> 3, kk_ = fid_ & 7; \
        bb = bfrag_f32(W_hh, 256, nt_ * 16 + lm, kk_ * 32 + c8_); } \
      else if (fid_ < FR_WHEAD) { int f2_ = fid_ - FR_WIH; \
        bb = bfrag_f32(W_ih, 64, (f2_ >> 1) * 16 + lm, (f2_ & 1) * 32 + c8_); } \
      else if (fid_ < FR_WLIFT) { int f3_ = fid_ - FR_WHEAD; \
        bb = bfrag_f32(W_head, 256, (f3_ >> 3) * 16 + lm, (f3_ & 7) * 32 + c8_); } \
      else { int f4_ = fid_ - FR_WLIFT; int nt_ = f4_ / 3, c_ = (f4_ % 3) * 32 + c8_; \
        _Pragma("unroll") \
        for (int j_ = 0; j_ < 8; ++j_) { int cc_ = c_ + j_; \
          bb[j_] = (f16)((cc_ < UU + PP) ? W_lift[(nt_ * 16 + lm) * 80 + cc_] : 0.f); } } \
    } } while (0)

  // ---- init ----
  for (int i = t; i < G3; i += NT) { sm.bih[i] = b_ih[i]; sm.bhh[i] = b_hh[i]; }
  if (t < THD) sm.bhead[t] = b_head[t];
  if (t < LL)  sm.blift[t] = b_lift[t];
  for (int i = t; i < UU * PP; i += NT) sm.jmp[i] = jump[i];
  for (int i = t; i < MB * HP; i += NT) sm.h_M[i] = (f16)0.f;
  float ho[8];
#pragma unroll
  for (int j = 0; j < 8; ++j) ho[j] = 0.f;
  const int fm = t >> 5, fp0 = (t & 31) * 2;
  float yr0 = y0[(size_t)(g16 + fm) * PP + fp0];
  float yr1 = y0[(size_t)(g16 + fm) * PP + fp0 + 1];
  sm.y[fm * YP + fp0] = yr0; sm.y[fm * YP + fp0 + 1] = yr1;
  if (t >= 256 && t < 320) { int l2 = t - 256; int m = l2 >> 2, q = l2 & 3;
    const float4* up = (const float4*)(u_seq + ((size_t)(g16 + m) * KK) * UU);
    *(float4*)&sm.u[0][m][q * 4] = up[q]; }
  if (t >= 320 && t < 336) sm.dt[0][t - 320] = dt_seq[(size_t)(g16 + (t - 320)) * KK];
  __syncthreads();

#pragma unroll 1
  for (int k = 0; k < KK; ++k) {
    const int cb = k & 1;

    // ---- A: build feat row-major + prefetch u/dt(k+1) ----
    {
      const int m = t >> 5, c0 = (t & 31) * 3;
#pragma unroll
      for (int i = 0; i < 3; ++i) {
        int c = c0 + i;   // 0..95
        float v = (c < UU) ? sm.u[cb][m][c] : sm.y[m * YP + (c - UU)];
        sm.f_M[m * FP + c] = (f16)v;
      }
      if (k + 1 < KK) {
        if (t >= 256 && t < 320) { int l2 = t - 256; int m2 = l2 >> 2, q = l2 & 3;
          const float4* up = (const float4*)(u_seq + ((size_t)(g16 + m2) * KK + (k + 1)) * UU);
          *(float4*)&sm.u[cb ^ 1][m2][q * 4] = up[q]; }
        if (t >= 320 && t < 336)
          sm.dt[cb ^ 1][t - 320] = dt_seq[(size_t)(g16 + (t - 320)) * KK + (k + 1)];
      }
    }
    __syncthreads();

    // ---- B: lift -> x (waves 0-3, n-tile wv) ----
    if (wv < 4) {
      const f16* frow = sm.f_M + lm * FP + lg * 8;
      f16x8 F0 = *(const f16x8*)(frow);
      f16x8 F1 = *(const f16x8*)(frow + 32);
      f16x8 F2 = *(const f16x8*)(frow + 64);
      f32x4 ax = {0.f, 0.f, 0.f, 0.f};
      f16x8 p_;
      BF(p_, FR_WLIFT + wv * 3 + 0); ax = MFMA(F0, p_, ax);
      BF(p_, FR_WLIFT + wv * 3 + 1); ax = MFMA(F1, p_, ax);
      BF(p_, FR_WLIFT + wv * 3 + 2); ax = MFMA(F2, p_, ax);
      const int c = wv * 16 + lm;
      const float bl = sm.blift[c];
#pragma unroll
      for (int r = 0; r < 4; ++r) {
        float v = ax[r] + bl;
        sm.x_M[(4 * lg + r) * XP + c] = (f16)(v * sigm(v));   // silu
      }
    }
    __syncthreads();

    // ---- C: gates. Wave wv owns r/z/n tiles {wv,wv+8},{16+wv,24+wv},{32+wv,40+wv} ----
    {
      const f16* hrow = sm.h_M + lm * HP + lg * 8;
      f16x8 H0 = *(const f16x8*)(hrow);
      f16x8 H1 = *(const f16x8*)(hrow + 32);
      f16x8 H2 = *(const f16x8*)(hrow + 64);
      f16x8 H3 = *(const f16x8*)(hrow + 96);
      f16x8 H4 = *(const f16x8*)(hrow + 128);
      f16x8 H5 = *(const f16x8*)(hrow + 160);
      f16x8 H6 = *(const f16x8*)(hrow + 192);
      f16x8 H7 = *(const f16x8*)(hrow + 224);
      const f16* xrow = sm.x_M + lm * XP + lg * 8;
      f16x8 X0 = *(const f16x8*)(xrow);
      f16x8 X1 = *(const f16x8*)(xrow + 32);
      __syncthreads();   // all reads of old h_M complete block-wide before writes

      f32x4 aR0 = {0.f,0.f,0.f,0.f}, aR1 = aR0, aZ0 = aR0, aZ1 = aR0;
      f32x4 aI0 = aR0, aI1 = aR0, aH0 = aR0, aH1 = aR0;

#define GEMM2_FULL(A0, A1, NT0, NT1) do { \
      f16x8 p_, q_; \
      BF(p_, FR_WIH + (NT0) * 2 + 0); BF(q_, FR_WIH + (NT1) * 2 + 0); \
      A0 = MFMA(X0, p_, A0); A1 = MFMA(X0, q_, A1); \
      BF(p_, FR_WIH + (NT0) * 2 + 1); BF(q_, FR_WIH + (NT1) * 2 + 1); \
      A0 = MFMA(X1, p_, A0); A1 = MFMA(X1, q_, A1); \
      BF(p_, FR_WHH + (NT0) * 8 + 0); BF(q_, FR_WHH + (NT1) * 8 + 0); \
      A0 = MFMA(H0, p_, A0); A1 = MFMA(H0, q_, A1); \
      BF(p_, FR_WHH + (NT0) * 8 + 1); BF(q_, FR_WHH + (NT1) * 8 + 1); \
      A0 = MFMA(H1, p_, A0); A1 = MFMA(H1, q_, A1); \
      BF(p_, FR_WHH + (NT0) * 8 + 2); BF(q_, FR_WHH + (NT1) * 8 + 2); \
      A0 = MFMA(H2, p_, A0); A1 = MFMA(H2, q_, A1); \
      BF(p_, FR_WHH + (NT0) * 8 + 3); BF(q_, FR_WHH + (NT1) * 8 + 3); \
      A0 = MFMA(H3, p_, A0); A1 = MFMA(H3, q_, A1); \
      BF(p_, FR_WHH + (NT0) * 8 + 4); BF(q_, FR_WHH + (NT1) * 8 + 4); \
      A0 = MFMA(H4, p_, A0); A1 = MFMA(H4, q_, A1); \
      BF(p_, FR_WHH + (NT0) * 8 + 5); BF(q_, FR_WHH + (NT1) * 8 + 5); \
      A0 = MFMA(H5, p_, A0); A1 = MFMA(H5, q_, A1); \
      BF(p_, FR_WHH + (NT0) * 8 + 6); BF(q_, FR_WHH + (NT1) * 8 + 6); \
      A0 = MFMA(H6, p_, A0); A1 = MFMA(H6, q_, A1); \
      BF(p_, FR_WHH + (NT0) * 8 + 7); BF(q_, FR_WHH + (NT1) * 8 + 7); \
      A0 = MFMA(H7, p_, A0); A1 = MFMA(H7, q_, A1); \
    } while (0)

#define GEMM2_IH(AI0, AI1, AH0, AH1, NT0, NT1) do { \
      f16x8 p_, q_; \
      BF(p_, FR_WIH + (NT0) * 2 + 0); BF(q_, FR_WIH + (NT1) * 2 + 0); \
      AI0 = MFMA(X0, p_, AI0); AI1 = MFMA(X0, q_, AI1); \
      BF(p_, FR_WIH + (NT0) * 2 + 1); BF(q_, FR_WIH + (NT1) * 2 + 1); \
      AI0 = MFMA(X1, p_, AI0); AI1 = MFMA(X1, q_, AI1); \
      BF(p_, FR_WHH + (NT0) * 8 + 0); BF(q_, FR_WHH + (NT1) * 8 + 0); \
      AH0 = MFMA(H0, p_, AH0); AH1 = MFMA(H0, q_, AH1); \
      BF(p_, FR_WHH + (NT0) * 8 + 1); BF(q_, FR_WHH + (NT1) * 8 + 1); \
      AH0 = MFMA(H1, p_, AH0); AH1 = MFMA(H1, q_, AH1); \
      BF(p_, FR_WHH + (NT0) * 8 + 2); BF(q_, FR_WHH + (NT1) * 8 + 2); \
      AH0 = MFMA(H2, p_, AH0); AH1 = MFMA(H2, q_, AH1); \
      BF(p_, FR_WHH + (NT0) * 8 + 3); BF(q_, FR_WHH + (NT1) * 8 + 3); \
      AH0 = MFMA(H3, p_, AH0); AH1 = MFMA(H3, q_, AH1); \
      BF(p_, FR_WHH + (NT0) * 8 + 4); BF(q_, FR_WHH + (NT1) * 8 + 4); \
      AH0 = MFMA(H4, p_, AH0); AH1 = MFMA(H4, q_, AH1); \
      BF(p_, FR_WHH + (NT0) * 8 + 5); BF(q_, FR_WHH + (NT1) * 8 + 5); \
      AH0 = MFMA(H5, p_, AH0); AH1 = MFMA(H5, q_, AH1); \
      BF(p_, FR_WHH + (NT0) * 8 + 6); BF(q_, FR_WHH + (NT1) * 8 + 6); \
      AH0 = MFMA(H6, p_, AH0); AH1 = MFMA(H6, q_, AH1); \
      BF(p_, FR_WHH + (NT0) * 8 + 7); BF(q_, FR_WHH + (NT1) * 8 + 7); \
      AH0 = MFMA(H7, p_, AH0); AH1 = MFMA(H7, q_, AH1); \
    } while (0)

      GEMM2_FULL(aR0, aR1, wv, wv + 8);
      GEMM2_FULL(aZ0, aZ1, 16 + wv, 24 + wv);
      GEMM2_IH(aI0, aI1, aH0, aH1, 32 + wv, 40 + wv);

      // in-register GRU update; scalar writeback to row-major h_M
      {
        const int c = wv * 16 + lm;
        const float br = sm.bih[c] + sm.bhh[c];
        const float bz = sm.bih[256 + c] + sm.bhh[256 + c];
        const float bi = sm.bih[512 + c];
        const float bh = sm.bhh[512 + c];
#pragma unroll
        for (int r = 0; r < 4; ++r) {
          float rr = sigm(aR0[r] + br);
          float zz = sigm(aZ0[r] + bz);
          float nn = 2.f * sigm(2.f * (aI0[r] + bi + rr * (aH0[r] + bh))) - 1.f;  // tanh
          float hv = (1.f - zz) * nn + zz * ho[r];
          ho[r] = hv;
          sm.h_M[(4 * lg + r) * HP + c] = (f16)hv;
        }
      }
      {
        const int c = (wv + 8) * 16 + lm;
        const float br = sm.bih[c] + sm.bhh[c];
        const float bz = sm.bih[256 + c] + sm.bhh[256 + c];
        const float bi = sm.bih[512 + c];
        const float bh = sm.bhh[512 + c];
#pragma unroll
        for (int r = 0; r < 4; ++r) {
          float rr = sigm(aR1[r] + br);
          float zz = sigm(aZ1[r] + bz);
          float nn = 2.f * sigm(2.f * (aI1[r] + bi + rr * (aH1[r] + bh))) - 1.f;
          float hv = (1.f - zz) * nn + zz * ho[4 + r];
          ho[4 + r] = hv;
          sm.h_M[(4 * lg + r) * HP + c] = (f16)hv;
        }
      }
    }
    __syncthreads();

    // ---- E: head -> theta (8 waves, one 16-unit tile each) ----
    {
      const f16* hrow = sm.h_M + lm * HP + lg * 8;
      f16x8 H0 = *(const f16x8*)(hrow);
      f16x8 H1 = *(const f16x8*)(hrow + 32);
      f16x8 H2 = *(const f16x8*)(hrow + 64);
      f16x8 H3 = *(const f16x8*)(hrow + 96);
      f16x8 H4 = *(const f16x8*)(hrow + 128);
      f16x8 H5 = *(const f16x8*)(hrow + 160);
      f16x8 H6 = *(const f16x8*)(hrow + 192);
      f16x8 H7 = *(const f16x8*)(hrow + 224);
      f32x4 th = {0.f, 0.f, 0.f, 0.f};
      f16x8 p_;
      BF(p_, FR_WHEAD + wv * 8 + 0); th = MFMA(H0, p_, th);
      BF(p_, FR_WHEAD + wv * 8 + 1); th = MFMA(H1, p_, th);
      BF(p_, FR_WHEAD + wv * 8 + 2); th = MFMA(H2, p_, th);
      BF(p_, FR_WHEAD + wv * 8 + 3); th = MFMA(H3, p_, th);
      BF(p_, FR_WHEAD + wv * 8 + 4); th = MFMA(H4, p_, th);
      BF(p_, FR_WHEAD + wv * 8 + 5); th = MFMA(H5, p_, th);
      BF(p_, FR_WHEAD + wv * 8 + 6); th = MFMA(H6, p_, th);
      BF(p_, FR_WHEAD + wv * 8 + 7); th = MFMA(H7, p_, th);
      const float bhd = sm.bhead[wv * 16 + lm];
#pragma unroll
      for (int r = 0; r < 4; ++r) {
        float raw = th[r] + bhd;
        sm.theta[(4 * lg + r) * TP + wv * 16 + lm] = 0.001f + 1.999f * sigm(raw);
      }
    }
    __syncthreads();

    // ---- F: jump + RK4 + clamp + global stores ----
    {
      const float hdt = sm.dt[cb][fm];
      float yv0, yv1;
#pragma unroll
      for (int e2 = 0; e2 < 2; ++e2) {
        int pp = fp0 + e2;
        float a = sm.theta[fm * TP + pp], dr = sm.theta[fm * TP + 64 + pp];
        float yv = (e2 == 0) ? yr0 : yr1;
#pragma unroll
        for (int uu = 0; uu < UU; ++uu) yv = fmaf(sm.u[cb][fm][uu], sm.jmp[uu * PP + pp], yv);
        float k1 = dr - a * yv;
        float k2 = dr - a * fmaf(0.5f * hdt, k1, yv);
        float k3 = dr - a * fmaf(0.5f * hdt, k2, yv);
        float k4 = dr - a * fmaf(hdt, k3, yv);
        yv = yv + (hdt * (1.f / 6.f)) * (k1 + 2.f * k2 + 2.f * k3 + k4);
        yv = fmaxf(yv, 0.f);
        if (e2 == 0) yv0 = yv; else yv1 = yv;
      }
      yr0 = yv0; yr1 = yv1;
      sm.y[fm * YP + fp0] = yv0; sm.y[fm * YP + fp0 + 1] = yv1;
      float2 y2; y2.x = yv0; y2.y = yv1;
      *(float2*)&out_y[((size_t)(g16 + fm) * KK + k) * PP + fp0] = y2;
      int j0 = (t & 31) * 4;
      *(float4*)&out_th[((size_t)(g16 + fm) * KK + k) * THD + j0] =
          *(const float4*)&sm.theta[fm * TP + j0];
    }
    __syncthreads();
  }
#undef BF
#undef GEMM2_FULL
#undef GEMM2_IH
}

extern "C" void kernel_launch(void* const* d_in, const int* in_sizes, int n_in,
                              void* d_out, int out_size, void* d_ws, size_t ws_size,
                              hipStream_t stream) {
  (void)in_sizes; (void)n_in; (void)out_size;
  const float* y0     = (const float*)d_in[0];
  const float* u_seq  = (const float*)d_in[1];
  const float* dt_seq = (const float*)d_in[2];
  const float* W_lift = (const float*)d_in[3];
  const float* b_lift = (const float*)d_in[4];
  const float* W_ih   = (const float*)d_in[5];
  const float* b_ih   = (const float*)d_in[6];
  const float* W_hh   = (const float*)d_in[7];
  const float* b_hh   = (const float*)d_in[8];
  const float* W_head = (const float*)d_in[9];
  const float* b_head = (const float*)d_in[10];
  const float* jump   = (const float*)d_in[11];
  float* out  = (float*)d_out;
  float* outy = out;
  float* outt = out + (size_t)BB * KK * PP;
  f16* ws16 = (f16*)d_ws;
  const bool packed = (ws_size >= (size_t)WS_REQ) && (d_ws != nullptr);
  if (packed) {
    pack_kernel<<<dim3((FR_TOTAL * 512 + 255) / 256), dim3(256), 0, stream>>>(
        W_lift, W_ih, W_hh, W_head, ws16);
    odernn_mfma<true><<<dim3(NG), dim3(NT), 0, stream>>>(
        y0, u_seq, dt_seq, W_lift, b_lift, W_ih, b_ih, W_hh, b_hh,
        W_head, b_head, jump, ws16, outy, outt);
  } else {
    odernn_mfma<false><<<dim3(NG), dim3(NT), 0, stream>>>(
        y0, u_seq, dt_seq, W_lift, b_lift, W_ih, b_ih, W_hh, b_hh,
        W_head, b_head, jump, ws16, outy, outt);
  }
}

// Round 9
// 4595.789 us; speedup vs baseline: 1.9888x; 1.1247x over previous
//
#include <hip/hip_runtime.h>
#include <hip/hip_bf16.h>

// Problem dims
#define BB 256
#define KK 512
#define UU 16
#define PP 64
#define HH 256
#define LL 64
#define THD 128   // 2*P
#define G3 768    // 3*H
#define MB 16     // batch rows per block
#define NG (BB/MB)  // 16 blocks
#define NT 512

// LDS row pitches (elements)
#define HP 264    // h_M pitch (f16)
#define XP 72     // x_M pitch (f16)
#define FP 104    // feat pitch (f16)
#define TP 132    // theta pitch (f32)

typedef _Float16 f16;
typedef _Float16 f16x8 __attribute__((ext_vector_type(8)));
typedef float f32x4 __attribute__((ext_vector_type(4)));

// fragment regions in d_ws (1KB per fragment = 64 lanes x 16B)
#define FR_WHH 0       // 48 nt * 8 kk = 384 frags
#define FR_WIH 384     // 48 nt * 2 kk = 96
#define FR_WHEAD 480   // 8 nt * 8 kk = 64
#define FR_WLIFT 544   // 4 nt * 3 kk = 12
#define FR_TOTAL 556
#define WS_REQ (FR_TOTAL * 1024)

__device__ __forceinline__ float sigm(float x) { return 1.f / (1.f + __expf(-x)); }

__device__ __forceinline__ f32x4 MFMA(f16x8 a, f16x8 b, f32x4 c) {
  return __builtin_amdgcn_mfma_f32_16x16x32_f16(a, b, c, 0, 0, 0);
}

// -------- pack kernel (unchanged, verified in R8) --------
__global__ void pack_kernel(const float* __restrict__ W_lift,
                            const float* __restrict__ W_ih,
                            const float* __restrict__ W_hh,
                            const float* __restrict__ W_head,
                            f16* __restrict__ ws) {
  int tid = blockIdx.x * 256 + threadIdx.x;
  if (tid >= FR_TOTAL * 512) return;
  int f = tid >> 9, l = (tid >> 3) & 63, j = tid & 7;
  int lm = l & 15, c8 = ((l >> 4) << 3) + j;
  float v;
  if (f < FR_WIH) { int nt = f >> 3, kk = f & 7; v = W_hh[(nt * 16 + lm) * 256 + kk * 32 + c8]; }
  else if (f < FR_WHEAD) { int f2 = f - FR_WIH; int nt = f2 >> 1, kk = f2 & 1;
    v = W_ih[(nt * 16 + lm) * 64 + kk * 32 + c8]; }
  else if (f < FR_WLIFT) { int f3 = f - FR_WHEAD; int nt = f3 >> 3, kk = f3 & 7;
    v = W_head[(nt * 16 + lm) * 256 + kk * 32 + c8]; }
  else { int f4 = f - FR_WLIFT; int nt = f4 / 3, kk = f4 % 3; int c = kk * 32 + c8;
    v = (c < UU + PP) ? W_lift[(nt * 16 + lm) * 80 + c] : 0.f; }
  ws[tid] = (f16)v;
}

// fallback b-frag from f32 weights (only when ws too small)
__device__ __forceinline__ f16x8 bfrag_f32(const float* W, int ldw, int n, int c) {
  const float* p = W + n * ldw + c;
  f16x8 r;
#pragma unroll
  for (int j = 0; j < 8; ++j) r[j] = (f16)p[j];
  return r;
}

struct SM {
  alignas(16) f16 h_M[2][MB * HP];   // double-buffered row-major [m][c]
  alignas(16) f16 x_M[MB * XP];
  alignas(16) f16 f_M[MB * FP];      // feat = [u(16)|y(64)|pad]
  alignas(16) float theta[MB * TP];
  alignas(16) float u[2][MB][UU];
  alignas(16) float jmp[UU * PP];
  float dt[2][MB];
  float bih[G3], bhh[G3], bhead[THD], blift[LL];
};

template<bool PACKED>
__global__ __launch_bounds__(NT) void odernn_mfma(
    const float* __restrict__ y0, const float* __restrict__ u_seq,
    const float* __restrict__ dt_seq, const float* __restrict__ W_lift,
    const float* __restrict__ b_lift, const float* __restrict__ W_ih,
    const float* __restrict__ b_ih, const float* __restrict__ W_hh,
    const float* __restrict__ b_hh, const float* __restrict__ W_head,
    const float* __restrict__ b_head, const float* __restrict__ jump,
    const f16* __restrict__ ws16,
    float* __restrict__ out_y, float* __restrict__ out_th) {
  __shared__ SM sm;
  const int t = threadIdx.x;
  const int lane = t & 63, wv = t >> 6;
  const int lm = lane & 15, lg = lane >> 4;
  const int g16 = blockIdx.x * MB;
  const f16x8* wsf = (const f16x8*)ws16;

#define BF(bb, FID) do { \
    if constexpr (PACKED) { bb = wsf[(FID) * 64 + lane]; } \
    else { int fid_ = (FID); int c8_ = lg << 3; \
      if (fid_ < FR_WIH) { int nt_ = fid_ >> 3, kk_ = fid_ & 7; \
        bb = bfrag_f32(W_hh, 256, nt_ * 16 + lm, kk_ * 32 + c8_); } \
      else if (fid_ < FR_WHEAD) { int f2_ = fid_ - FR_WIH; \
        bb = bfrag_f32(W_ih, 64, (f2_ >> 1) * 16 + lm, (f2_ & 1) * 32 + c8_); } \
      else if (fid_ < FR_WLIFT) { int f3_ = fid_ - FR_WHEAD; \
        bb = bfrag_f32(W_head, 256, (f3_ >> 3) * 16 + lm, (f3_ & 7) * 32 + c8_); } \
      else { int f4_ = fid_ - FR_WLIFT; int nt_ = f4_ / 3, c_ = (f4_ % 3) * 32 + c8_; \
        _Pragma("unroll") \
        for (int j_ = 0; j_ < 8; ++j_) { int cc_ = c_ + j_; \
          bb[j_] = (f16)((cc_ < UU + PP) ? W_lift[(nt_ * 16 + lm) * 80 + cc_] : 0.f); } } \
    } } while (0)

  // ---- init ----
  for (int i = t; i < G3; i += NT) { sm.bih[i] = b_ih[i]; sm.bhh[i] = b_hh[i]; }
  if (t < THD) sm.bhead[t] = b_head[t];
  if (t < LL)  sm.blift[t] = b_lift[t];
  for (int i = t; i < UU * PP; i += NT) sm.jmp[i] = jump[i];
  for (int i = t; i < MB * HP; i += NT) sm.h_M[0][i] = (f16)0.f;
  float ho[8];
#pragma unroll
  for (int j = 0; j < 8; ++j) ho[j] = 0.f;
  const int fm = t >> 5, fp0 = (t & 31) * 2;
  float yr0 = y0[(size_t)(g16 + fm) * PP + fp0];
  float yr1 = y0[(size_t)(g16 + fm) * PP + fp0 + 1];
  {  // feat for k=0 : [u0 | y0]
    const int m = t >> 5, c0 = (t & 31) * 3;
#pragma unroll
    for (int i = 0; i < 3; ++i) {
      int c = c0 + i;  // 0..95
      float v = (c < UU) ? u_seq[((size_t)(g16 + m) * KK) * UU + c]
                         : y0[(size_t)(g16 + m) * PP + (c - UU)];
      sm.f_M[m * FP + c] = (f16)v;
    }
  }
  if (t >= 256 && t < 320) { int l2 = t - 256; int m = l2 >> 2, q = l2 & 3;
    const float4* up = (const float4*)(u_seq + ((size_t)(g16 + m) * KK) * UU);
    *(float4*)&sm.u[0][m][q * 4] = up[q]; }
  if (t >= 320 && t < 336) sm.dt[0][t - 320] = dt_seq[(size_t)(g16 + (t - 320)) * KK];
  __syncthreads();

  int hb = 0;
#pragma unroll 1
  for (int k = 0; k < KK; ++k) {
    const int cb = k & 1, nb = cb ^ 1;

    // ---- B: lift (waves 0-3) ; u/dt prefetch (waves 4-7) ----
    if (wv < 4) {
      const f16* frow = sm.f_M + lm * FP + lg * 8;
      f16x8 F0 = *(const f16x8*)(frow);
      f16x8 F1 = *(const f16x8*)(frow + 32);
      f16x8 F2 = *(const f16x8*)(frow + 64);
      f16x8 p0, p1, p2;
      BF(p0, FR_WLIFT + wv * 3 + 0);
      BF(p1, FR_WLIFT + wv * 3 + 1);
      BF(p2, FR_WLIFT + wv * 3 + 2);
      f32x4 ax = {0.f, 0.f, 0.f, 0.f};
      ax = MFMA(F0, p0, ax); ax = MFMA(F1, p1, ax); ax = MFMA(F2, p2, ax);
      const int c = wv * 16 + lm;
      const float bl = sm.blift[c];
#pragma unroll
      for (int r = 0; r < 4; ++r) {
        float v = ax[r] + bl;
        sm.x_M[(4 * lg + r) * XP + c] = (f16)(v * sigm(v));   // silu
      }
    } else if (k + 1 < KK) {
      if (t >= 256 && t < 320) { int l2 = t - 256; int m2 = l2 >> 2, q = l2 & 3;
        const float4* up = (const float4*)(u_seq + ((size_t)(g16 + m2) * KK + (k + 1)) * UU);
        *(float4*)&sm.u[nb][m2][q * 4] = up[q]; }
      if (t >= 320 && t < 336)
        sm.dt[nb][t - 320] = dt_seq[(size_t)(g16 + (t - 320)) * KK + (k + 1)];
    }
    __syncthreads();

    // ---- C: gate GEMM, 30-stage 4-deep pipelined fragment stream ----
    {
      const f16* hrow = sm.h_M[hb] + lm * HP + lg * 8;
      f16x8 H0 = *(const f16x8*)(hrow);
      f16x8 H1 = *(const f16x8*)(hrow + 32);
      f16x8 H2 = *(const f16x8*)(hrow + 64);
      f16x8 H3 = *(const f16x8*)(hrow + 96);
      f16x8 H4 = *(const f16x8*)(hrow + 128);
      f16x8 H5 = *(const f16x8*)(hrow + 160);
      f16x8 H6 = *(const f16x8*)(hrow + 192);
      f16x8 H7 = *(const f16x8*)(hrow + 224);
      const f16* xrow = sm.x_M + lm * XP + lg * 8;
      f16x8 X0 = *(const f16x8*)(xrow);
      f16x8 X1 = *(const f16x8*)(xrow + 32);

      f32x4 aR0 = {0.f,0.f,0.f,0.f}, aR1 = aR0, aZ0 = aR0, aZ1 = aR0;
      f32x4 aI0 = aR0, aI1 = aR0, aH0 = aR0, aH1 = aR0;
      f16x8 s0p, s0q, s1p, s1q, s2p, s2q, s3p, s3q;

#define LDP(SL, F0_, F1_) BF(SL##p, F0_); BF(SL##q, F1_);
#define MMA(SL, A_, A0_, A1_) A0_ = MFMA(A_, SL##p, A0_); A1_ = MFMA(A_, SL##q, A1_);

      LDP(s0, FR_WIH + wv * 2 + 0,        FR_WIH + (wv + 8) * 2 + 0)
      LDP(s1, FR_WIH + wv * 2 + 1,        FR_WIH + (wv + 8) * 2 + 1)
      LDP(s2, FR_WHH + wv * 8 + 0,        FR_WHH + (wv + 8) * 8 + 0)
      LDP(s3, FR_WHH + wv * 8 + 1,        FR_WHH + (wv + 8) * 8 + 1)
      MMA(s0, X0, aR0, aR1) LDP(s0, FR_WHH + wv * 8 + 2, FR_WHH + (wv + 8) * 8 + 2)
      MMA(s1, X1, aR0, aR1) LDP(s1, FR_WHH + wv * 8 + 3, FR_WHH + (wv + 8) * 8 + 3)
      MMA(s2, H0, aR0, aR1) LDP(s2, FR_WHH + wv * 8 + 4, FR_WHH + (wv + 8) * 8 + 4)
      MMA(s3, H1, aR0, aR1) LDP(s3, FR_WHH + wv * 8 + 5, FR_WHH + (wv + 8) * 8 + 5)
      MMA(s0, H2, aR0, aR1) LDP(s0, FR_WHH + wv * 8 + 6, FR_WHH + (wv + 8) * 8 + 6)
      MMA(s1, H3, aR0, aR1) LDP(s1, FR_WHH + wv * 8 + 7, FR_WHH + (wv + 8) * 8 + 7)
      MMA(s2, H4, aR0, aR1) LDP(s2, FR_WIH + (16 + wv) * 2 + 0, FR_WIH + (24 + wv) * 2 + 0)
      MMA(s3, H5, aR0, aR1) LDP(s3, FR_WIH + (16 + wv) * 2 + 1, FR_WIH + (24 + wv) * 2 + 1)
      MMA(s0, H6, aR0, aR1) LDP(s0, FR_WHH + (16 + wv) * 8 + 0, FR_WHH + (24 + wv) * 8 + 0)
      MMA(s1, H7, aR0, aR1) LDP(s1, FR_WHH + (16 + wv) * 8 + 1, FR_WHH + (24 + wv) * 8 + 1)
      MMA(s2, X0, aZ0, aZ1) LDP(s2, FR_WHH + (16 + wv) * 8 + 2, FR_WHH + (24 + wv) * 8 + 2)
      MMA(s3, X1, aZ0, aZ1) LDP(s3, FR_WHH + (16 + wv) * 8 + 3, FR_WHH + (24 + wv) * 8 + 3)
      MMA(s0, H0, aZ0, aZ1) LDP(s0, FR_WHH + (16 + wv) * 8 + 4, FR_WHH + (24 + wv) * 8 + 4)
      MMA(s1, H1, aZ0, aZ1) LDP(s1, FR_WHH + (16 + wv) * 8 + 5, FR_WHH + (24 + wv) * 8 + 5)
      MMA(s2, H2, aZ0, aZ1) LDP(s2, FR_WHH + (16 + wv) * 8 + 6, FR_WHH + (24 + wv) * 8 + 6)
      MMA(s3, H3, aZ0, aZ1) LDP(s3, FR_WHH + (16 + wv) * 8 + 7, FR_WHH + (24 + wv) * 8 + 7)
      MMA(s0, H4, aZ0, aZ1) LDP(s0, FR_WIH + (32 + wv) * 2 + 0, FR_WIH + (40 + wv) * 2 + 0)
      MMA(s1, H5, aZ0, aZ1) LDP(s1, FR_WIH + (32 + wv) * 2 + 1, FR_WIH + (40 + wv) * 2 + 1)
      MMA(s2, H6, aZ0, aZ1) LDP(s2, FR_WHH + (32 + wv) * 8 + 0, FR_WHH + (40 + wv) * 8 + 0)
      MMA(s3, H7, aZ0, aZ1) LDP(s3, FR_WHH + (32 + wv) * 8 + 1, FR_WHH + (40 + wv) * 8 + 1)
      MMA(s0, X0, aI0, aI1) LDP(s0, FR_WHH + (32 + wv) * 8 + 2, FR_WHH + (40 + wv) * 8 + 2)
      MMA(s1, X1, aI0, aI1) LDP(s1, FR_WHH + (32 + wv) * 8 + 3, FR_WHH + (40 + wv) * 8 + 3)
      MMA(s2, H0, aH0, aH1) LDP(s2, FR_WHH + (32 + wv) * 8 + 4, FR_WHH + (40 + wv) * 8 + 4)
      MMA(s3, H1, aH0, aH1) LDP(s3, FR_WHH + (32 + wv) * 8 + 5, FR_WHH + (40 + wv) * 8 + 5)
      MMA(s0, H2, aH0, aH1) LDP(s0, FR_WHH + (32 + wv) * 8 + 6, FR_WHH + (40 + wv) * 8 + 6)
      MMA(s1, H3, aH0, aH1) LDP(s1, FR_WHH + (32 + wv) * 8 + 7, FR_WHH + (40 + wv) * 8 + 7)
      MMA(s2, H4, aH0, aH1)
      MMA(s3, H5, aH0, aH1)
      MMA(s0, H6, aH0, aH1)
      MMA(s1, H7, aH0, aH1)
#undef LDP
#undef MMA

      // in-register GRU update; write NEW h buffer (no extra barrier needed)
      f16* hnew = sm.h_M[hb ^ 1];
      {
        const int c = wv * 16 + lm;
        const float br = sm.bih[c] + sm.bhh[c];
        const float bz = sm.bih[256 + c] + sm.bhh[256 + c];
        const float bi = sm.bih[512 + c];
        const float bh = sm.bhh[512 + c];
#pragma unroll
        for (int r = 0; r < 4; ++r) {
          float rr = sigm(aR0[r] + br);
          float zz = sigm(aZ0[r] + bz);
          float nn = 2.f * sigm(2.f * (aI0[r] + bi + rr * (aH0[r] + bh))) - 1.f;  // tanh
          float hv = (1.f - zz) * nn + zz * ho[r];
          ho[r] = hv;
          hnew[(4 * lg + r) * HP + c] = (f16)hv;
        }
      }
      {
        const int c = (wv + 8) * 16 + lm;
        const float br = sm.bih[c] + sm.bhh[c];
        const float bz = sm.bih[256 + c] + sm.bhh[256 + c];
        const float bi = sm.bih[512 + c];
        const float bh = sm.bhh[512 + c];
#pragma unroll
        for (int r = 0; r < 4; ++r) {
          float rr = sigm(aR1[r] + br);
          float zz = sigm(aZ1[r] + bz);
          float nn = 2.f * sigm(2.f * (aI1[r] + bi + rr * (aH1[r] + bh))) - 1.f;
          float hv = (1.f - zz) * nn + zz * ho[4 + r];
          ho[4 + r] = hv;
          hnew[(4 * lg + r) * HP + c] = (f16)hv;
        }
      }
    }
    __syncthreads();

    // ---- E: head -> theta (8 waves, one 16-col tile each; depth-4 pipeline) ----
    {
      const f16* hrow = sm.h_M[hb ^ 1] + lm * HP + lg * 8;
      f16x8 H0 = *(const f16x8*)(hrow);
      f16x8 H1 = *(const f16x8*)(hrow + 32);
      f16x8 H2 = *(const f16x8*)(hrow + 64);
      f16x8 H3 = *(const f16x8*)(hrow + 96);
      f16x8 H4 = *(const f16x8*)(hrow + 128);
      f16x8 H5 = *(const f16x8*)(hrow + 160);
      f16x8 H6 = *(const f16x8*)(hrow + 192);
      f16x8 H7 = *(const f16x8*)(hrow + 224);
      f16x8 e0, e1, e2, e3;
      BF(e0, FR_WHEAD + wv * 8 + 0);
      BF(e1, FR_WHEAD + wv * 8 + 1);
      BF(e2, FR_WHEAD + wv * 8 + 2);
      BF(e3, FR_WHEAD + wv * 8 + 3);
      f32x4 th = {0.f, 0.f, 0.f, 0.f};
      th = MFMA(H0, e0, th); BF(e0, FR_WHEAD + wv * 8 + 4);
      th = MFMA(H1, e1, th); BF(e1, FR_WHEAD + wv * 8 + 5);
      th = MFMA(H2, e2, th); BF(e2, FR_WHEAD + wv * 8 + 6);
      th = MFMA(H3, e3, th); BF(e3, FR_WHEAD + wv * 8 + 7);
      th = MFMA(H4, e0, th);
      th = MFMA(H5, e1, th);
      th = MFMA(H6, e2, th);
      th = MFMA(H7, e3, th);
      const float bhd = sm.bhead[wv * 16 + lm];
#pragma unroll
      for (int r = 0; r < 4; ++r) {
        float raw = th[r] + bhd;
        sm.theta[(4 * lg + r) * TP + wv * 16 + lm] = 0.001f + 1.999f * sigm(raw);
      }
    }
    __syncthreads();

    // ---- F: jump + RK4 + clamp + stores + write feat for k+1 ----
    {
      const float hdt = sm.dt[cb][fm];
      float yv0, yv1;
#pragma unroll
      for (int e2 = 0; e2 < 2; ++e2) {
        int pp = fp0 + e2;
        float a = sm.theta[fm * TP + pp], dr = sm.theta[fm * TP + 64 + pp];
        float yv = (e2 == 0) ? yr0 : yr1;
#pragma unroll
        for (int uu = 0; uu < UU; ++uu) yv = fmaf(sm.u[cb][fm][uu], sm.jmp[uu * PP + pp], yv);
        float k1 = dr - a * yv;
        float k2 = dr - a * fmaf(0.5f * hdt, k1, yv);
        float k3 = dr - a * fmaf(0.5f * hdt, k2, yv);
        float k4 = dr - a * fmaf(hdt, k3, yv);
        yv = yv + (hdt * (1.f / 6.f)) * (k1 + 2.f * k2 + 2.f * k3 + k4);
        yv = fmaxf(yv, 0.f);
        if (e2 == 0) yv0 = yv; else yv1 = yv;
      }
      yr0 = yv0; yr1 = yv1;
      // feat y-part for step k+1
      sm.f_M[fm * FP + UU + fp0] = (f16)yv0;
      sm.f_M[fm * FP + UU + fp0 + 1] = (f16)yv1;
      // feat u-part for step k+1 (u[k+1] prefetched into sm.u[nb] during B)
      if ((t & 31) < 8) {
        int cu = (t & 31) * 2;
        sm.f_M[fm * FP + cu] = (f16)sm.u[nb][fm][cu];
        sm.f_M[fm * FP + cu + 1] = (f16)sm.u[nb][fm][cu + 1];
      }
      float2 y2; y2.x = yv0; y2.y = yv1;
      *(float2*)&out_y[((size_t)(g16 + fm) * KK + k) * PP + fp0] = y2;
      int j0 = (t & 31) * 4;
      *(float4*)&out_th[((size_t)(g16 + fm) * KK + k) * THD + j0] =
          *(const float4*)&sm.theta[fm * TP + j0];
    }
    __syncthreads();
    hb ^= 1;
  }
#undef BF
}

extern "C" void kernel_launch(void* const* d_in, const int* in_sizes, int n_in,
                              void* d_out, int out_size, void* d_ws, size_t ws_size,
                              hipStream_t stream) {
  (void)in_sizes; (void)n_in; (void)out_size;
  const float* y0     = (const float*)d_in[0];
  const float* u_seq  = (const float*)d_in[1];
  const float* dt_seq = (const float*)d_in[2];
  const float* W_lift = (const float*)d_in[3];
  const float* b_lift = (const float*)d_in[4];
  const float* W_ih   = (const float*)d_in[5];
  const float* b_ih   = (const float*)d_in[6];
  const float* W_hh   = (const float*)d_in[7];
  const float* b_hh   = (const float*)d_in[8];
  const float* W_head = (const float*)d_in[9];
  const float* b_head = (const float*)d_in[10];
  const float* jump   = (const float*)d_in[11];
  float* out  = (float*)d_out;
  float* outy = out;
  float* outt = out + (size_t)BB * KK * PP;
  f16* ws16 = (f16*)d_ws;
  const bool packed = (ws_size >= (size_t)WS_REQ) && (d_ws != nullptr);
  if (packed) {
    pack_kernel<<<dim3((FR_TOTAL * 512 + 255) / 256), dim3(256), 0, stream>>>(
        W_lift, W_ih, W_hh, W_head, ws16);
    odernn_mfma<true><<<dim3(NG), dim3(NT), 0, stream>>>(
        y0, u_seq, dt_seq, W_lift, b_lift, W_ih, b_ih, W_hh, b_hh,
        W_head, b_head, jump, ws16, outy, outt);
  } else {
    odernn_mfma<false><<<dim3(NG), dim3(NT), 0, stream>>>(
        y0, u_seq, dt_seq, W_lift, b_lift, W_ih, b_ih, W_hh, b_hh,
        W_head, b_head, jump, ws16, outy, outt);
  }
}